// Round 13
// baseline (11506.243 us; speedup 1.0000x reference)
//
#include <hip/hip_runtime.h>

typedef unsigned short u16;
typedef __attribute__((ext_vector_type(8))) short short8;
typedef __attribute__((ext_vector_type(4))) float f32x4;

__device__ __forceinline__ float b2f(u16 h) {
  union { unsigned int u; float f; } v; v.u = ((unsigned int)h) << 16; return v.f;
}
__device__ __forceinline__ u16 f2b(float f) {
  union { float f; unsigned int u; } v; v.f = f;
  return (u16)((v.u + 0x7fffu + ((v.u >> 16) & 1u)) >> 16);
}

#define SENC 1025
#define SPENC 1032
#define NBE 129
#define SDEC 1024
#define NBD 128
#define BATCH 32
#define MENC (BATCH * SPENC)  /* 33024 */
#define MDEC (BATCH * SDEC)   /* 32768 */

// ---------- beacon ----------
__global__ void beacon_k(float* out) { if (threadIdx.x == 0) out[0] = 1000.0f; }

// ---------- weight transpose + bf16 convert: WT[n][k] = bf16(W[k][n]) ----------
__global__ __launch_bounds__(256) void tr_k(const float* __restrict__ W, u16* __restrict__ WT, int K, int N)
{
  __shared__ float sm[32][33];
  int k0 = blockIdx.x * 32, n0 = blockIdx.y * 32;
  const float* Wz = W + (size_t)blockIdx.z * K * N;
  u16* WTz = WT + (size_t)blockIdx.z * K * N;
  int r = threadIdx.x >> 3, c0 = (threadIdx.x & 7) * 4;
  float4 v = *(const float4*)&Wz[(size_t)(k0 + r) * N + n0 + c0];
  sm[r][c0] = v.x; sm[r][c0 + 1] = v.y; sm[r][c0 + 2] = v.z; sm[r][c0 + 3] = v.w;
  __syncthreads();
  ushort4 u;
  u.x = f2b(sm[c0][r]); u.y = f2b(sm[c0 + 1][r]); u.z = f2b(sm[c0 + 2][r]); u.w = f2b(sm[c0 + 3][r]);
  *(ushort4*)&WTz[(size_t)(n0 + r) * K + k0 + c0] = u;
}

// ---------- embed: h fp32 + hb bf16 ----------
__global__ __launch_bounds__(256) void embed_k(const float* __restrict__ x, const float* __restrict__ Wd,
    const float* __restrict__ bd, const float* __restrict__ emb, float* __restrict__ h, u16* __restrict__ hb)
{
  size_t gid = (size_t)blockIdx.x * 256 + threadIdx.x;  // MENC*512
  int dd = (int)(gid & 511);
  size_t rs = gid >> 9;
  int s = (int)(rs % SPENC);
  int b = (int)(rs / SPENC);
  float v;
  if (s == 0) {
    v = emb[dd];
  } else if (s < SENC) {
    float acc = bd[dd];
    const float* xr = x + ((size_t)b * 1024 + (s - 1)) * 16;
    #pragma unroll
    for (int j = 0; j < 16; ++j) acc += xr[j] * Wd[j * 512 + dd];
    v = acc + emb[(size_t)s * 512 + dd];
  } else {
    v = 0.f;
  }
  h[gid] = v;
  hb[gid] = f2b(v);
}

// ---------- MFMA bf16 GEMM, 128x256 tile, 512 threads (8 waves), LDS-FREE ----------
// Fragments loaded DIRECTLY from global (L2-hot; B panels <= 2MB fit per-XCD L2).
// One frag-load instruction = 16 rows x 64B lines, fully coalesced. No barriers in K-loop.
// Register ping-pong prefetch (2-way, static names per rule #20). Requires nt even (K%64==0).
template<bool RELU>
__global__ __launch_bounds__(512) void mgemm_k(const u16* __restrict__ A, const u16* __restrict__ WT,
    const float* __restrict__ bias, u16* __restrict__ C,
    int M, int N, int Kc, int lda, int ldb)
{
  int t = threadIdx.x;

  // bijective XCD-aware remap of the flattened (x,y) id (L2 locality for shared panels)
  int gx = gridDim.x;
  int nwg = gx * gridDim.y;
  int flat = blockIdx.y * gx + blockIdx.x;
  int q = nwg >> 3, rr = nwg & 7;
  int xcd = flat & 7, idx = flat >> 3;
  int swz = (xcd < rr ? xcd * (q + 1) : rr * (q + 1) + (xcd - rr) * q) + idx;
  int bx = swz % gx, by = swz / gx;

  int n0 = bx * 256, m0 = by * 128;
  int lane = t & 63, wave = t >> 6;            // 8 waves: 2M x 4N
  int wm = (wave >> 2) * 64, wn = (wave & 3) * 64;
  int quad = lane >> 4, l15 = lane & 15;

  const u16* aB = A  + (size_t)(m0 + wm + l15) * lda + quad * 8;
  const u16* bB = WT + (size_t)(n0 + wn + l15) * ldb + quad * 8;

  f32x4 acc[4][4];
  #pragma unroll
  for (int i = 0; i < 4; ++i)
    #pragma unroll
    for (int j = 0; j < 4; ++j) acc[i][j] = (f32x4){0.f, 0.f, 0.f, 0.f};

  const int nt = Kc >> 5;   // even at all call sites (K = 512 or 2048)
  short8 afA[4], bfA[4], afB[4], bfB[4];
  #pragma unroll
  for (int i = 0; i < 4; ++i) afA[i] = *(const short8*)(aB + (size_t)i * 16 * lda);
  #pragma unroll
  for (int j = 0; j < 4; ++j) bfA[j] = *(const short8*)(bB + (size_t)j * 16 * ldb);

  for (int kk = 0; kk < nt; kk += 2) {
    int ko1 = (kk + 1) << 5;
    #pragma unroll
    for (int i = 0; i < 4; ++i) afB[i] = *(const short8*)(aB + (size_t)i * 16 * lda + ko1);
    #pragma unroll
    for (int j = 0; j < 4; ++j) bfB[j] = *(const short8*)(bB + (size_t)j * 16 * ldb + ko1);
    #pragma unroll
    for (int i = 0; i < 4; ++i)
      #pragma unroll
      for (int j = 0; j < 4; ++j)
        acc[i][j] = __builtin_amdgcn_mfma_f32_16x16x32_bf16(afA[i], bfA[j], acc[i][j], 0, 0, 0);
    if (kk + 2 < nt) {
      int ko2 = (kk + 2) << 5;
      #pragma unroll
      for (int i = 0; i < 4; ++i) afA[i] = *(const short8*)(aB + (size_t)i * 16 * lda + ko2);
      #pragma unroll
      for (int j = 0; j < 4; ++j) bfA[j] = *(const short8*)(bB + (size_t)j * 16 * ldb + ko2);
    }
    #pragma unroll
    for (int i = 0; i < 4; ++i)
      #pragma unroll
      for (int j = 0; j < 4; ++j)
        acc[i][j] = __builtin_amdgcn_mfma_f32_16x16x32_bf16(afB[i], bfB[j], acc[i][j], 0, 0, 0);
  }

  // epilogue: D row = quad*4+reg (m), col = lane&15 (n)  [m89-verified]
  #pragma unroll
  for (int i = 0; i < 4; ++i) {
    int mBase = m0 + wm + i * 16 + quad * 4;
    #pragma unroll
    for (int r = 0; r < 4; ++r) {
      int m = mBase + r;
      if (m < M) {
        #pragma unroll
        for (int j = 0; j < 4; ++j) {
          int n = n0 + wn + j * 16 + l15;
          float v = acc[i][j][r] + bias[n];
          if (RELU) v = fmaxf(v, 0.f);
          C[(size_t)m * N + n] = f2b(v);
        }
      }
    }
  }
}

// ---------- fused GEMM(N=512) + residual + LayerNorm, 128M x 512N, LDS-FREE frags ----------
// One block owns 128 rows x ALL 512 cols; grid = M/128. 8 waves (2M x 4N), per-wave
// 64x128 (acc[4][8]). Fragments direct from global (B <= 2MB, L2-hot). No K-loop barriers.
// Epilogue: v = acc + bias + h (f32); row mean/var via quad-shfl + 4-wide LDS cross-wave
// reduce; writes h (fp32) and hb (bf16). Requires M % 128 == 0 and K % 32 == 0.
__global__ __launch_bounds__(512) void mgemmln_k(const u16* __restrict__ A, const u16* __restrict__ WT,
    const float* __restrict__ bias, float* __restrict__ h, u16* __restrict__ hb,
    const float* __restrict__ g, const float* __restrict__ bbv_,
    int M, int Kc, int lda)
{
  __shared__ float redS[128][4], redQ[128][4];    // 4 KB
  int t = threadIdx.x;
  int m0 = blockIdx.x * 128;
  int lane = t & 63, wave = t >> 6;               // 8 waves: 2M x 4N
  int wm = (wave >> 2) * 64, wn = (wave & 3) * 128;
  int quad = lane >> 4, l15 = lane & 15;
  int wnid = wave & 3;

  const u16* aB = A  + (size_t)(m0 + wm + l15) * lda + quad * 8;
  const u16* bB = WT + (size_t)(wn + l15) * Kc + quad * 8;

  f32x4 acc[4][8];
  #pragma unroll
  for (int i = 0; i < 4; ++i)
    #pragma unroll
    for (int j = 0; j < 8; ++j) acc[i][j] = (f32x4){0.f, 0.f, 0.f, 0.f};

  const int nt = Kc >> 5;
  for (int kk = 0; kk < nt; ++kk) {
    int ko = kk << 5;
    short8 af[4], bf[8];
    #pragma unroll
    for (int i = 0; i < 4; ++i) af[i] = *(const short8*)(aB + (size_t)i * 16 * lda + ko);
    #pragma unroll
    for (int j = 0; j < 8; ++j) bf[j] = *(const short8*)(bB + (size_t)j * 16 * Kc + ko);
    #pragma unroll
    for (int i = 0; i < 4; ++i)
      #pragma unroll
      for (int j = 0; j < 8; ++j)
        acc[i][j] = __builtin_amdgcn_mfma_f32_16x16x32_bf16(af[i], bf[j], acc[i][j], 0, 0, 0);
  }

  // ---------- epilogue: residual add + row stats ----------
  float bsv[8];
  #pragma unroll
  for (int j = 0; j < 8; ++j) bsv[j] = bias[wn + j * 16 + l15];

  #pragma unroll
  for (int i = 0; i < 4; ++i) {
    #pragma unroll
    for (int r = 0; r < 4; ++r) {
      int lr = wm + i * 16 + quad * 4 + r;
      const float* hrow = h + (size_t)(m0 + lr) * 512 + wn + l15;
      float s = 0.f, qq = 0.f;
      #pragma unroll
      for (int j = 0; j < 8; ++j) {
        float v = acc[i][j][r] + bsv[j] + hrow[j * 16];
        acc[i][j][r] = v;
        s += v; qq += v * v;
      }
      #pragma unroll
      for (int off = 1; off < 16; off <<= 1) {
        s += __shfl_xor(s, off);
        qq += __shfl_xor(qq, off);
      }
      if (l15 == 0) { redS[lr][wnid] = s; redQ[lr][wnid] = qq; }
    }
  }
  __syncthreads();
  float gv[8], bv[8];
  #pragma unroll
  for (int j = 0; j < 8; ++j) {
    gv[j] = g[wn + j * 16 + l15];
    bv[j] = bbv_[wn + j * 16 + l15];
  }
  #pragma unroll
  for (int i = 0; i < 4; ++i) {
    #pragma unroll
    for (int r = 0; r < 4; ++r) {
      int lr = wm + i * 16 + quad * 4 + r;
      float s = redS[lr][0] + redS[lr][1] + redS[lr][2] + redS[lr][3];
      float qq = redQ[lr][0] + redQ[lr][1] + redQ[lr][2] + redQ[lr][3];
      float mean = s * (1.f / 512.f);
      float var = fmaxf(qq * (1.f / 512.f) - mean * mean, 0.f);
      float rinv = rsqrtf(var + 1e-5f);
      float* hrow = h + (size_t)(m0 + lr) * 512 + wn + l15;
      u16* hbrow = hb + (size_t)(m0 + lr) * 512 + wn + l15;
      #pragma unroll
      for (int j = 0; j < 8; ++j) {
        float o = (acc[i][j][r] - mean) * rinv * gv[j] + bv[j];
        hrow[j * 16] = o;
        hbrow[j * 16] = f2b(o);
      }
    }
  }
}

// ---------- sparse block attention, MFMA version: one wave per (b, h, n) ----------
__global__ __launch_bounds__(64) void attnm_k(const u16* __restrict__ qkv, u16* __restrict__ av,
    const int* __restrict__ rnd, int S, int Sp, int nb)
{
  __shared__ __align__(16) u16 Vt[64 * 104];
  __shared__ __align__(16) u16 Pl[16 * 104];
  __shared__ int sJB[10], sVD[10];
  int t = threadIdx.x;
  int n = blockIdx.x % nb;
  int r1 = blockIdx.x / nb;
  int hh = r1 & 7, b = r1 >> 3;
  const u16* base = qkv + (size_t)b * Sp * 1536;
  int l15 = t & 15, quad = t >> 4;

  if (t < 10) {
    int jb, vd;
    if (t < 2) { jb = t; vd = 1; }
    else if (t < 7) {
      int w = n + t - 4;
      vd = (w >= 0 && w < nb) ? 1 : 0;
      jb = w < 0 ? 0 : (w > nb - 1 ? nb - 1 : w);
    } else { jb = rnd[n * 3 + t - 7]; vd = 1; }
    sJB[t] = jb; sVD[t] = vd;
  }
  {
    f32x4 zz = {0.f, 0.f, 0.f, 0.f};
    *(f32x4*)&Vt[t * 104 + 80] = zz;
    *(f32x4*)&Vt[t * 104 + 88] = zz;
    if (t < 16) {
      *(f32x4*)&Pl[t * 104 + 80] = zz;
      *(f32x4*)&Pl[t * 104 + 88] = zz;
    }
  }
  __syncthreads();

  short8 aq0, aq1;
  {
    const u16* qp = base + (size_t)(n * 8 + (l15 & 7)) * 1536 + hh * 64 + quad * 8;
    aq0 = *(const short8*)qp;
    aq1 = *(const short8*)(qp + 32);
  }

  f32x4 s[5];
  float okm[5];
  #pragma unroll
  for (int tile = 0; tile < 5; ++tile) {
    int kb = tile * 2 + (l15 >> 3);
    int tok = sJB[kb] * 8 + (l15 & 7);
    okm[tile] = (sVD[kb] && tok < S) ? 0.f : -3.0e38f;
    const u16* kp = base + (size_t)tok * 1536 + 512 + hh * 64 + quad * 8;
    short8 k0 = *(const short8*)kp;
    short8 k1 = *(const short8*)(kp + 32);
    f32x4 c = {0.f, 0.f, 0.f, 0.f};
    c = __builtin_amdgcn_mfma_f32_16x16x32_bf16(aq0, k0, c, 0, 0, 0);
    c = __builtin_amdgcn_mfma_f32_16x16x32_bf16(aq1, k1, c, 0, 0, 0);
    s[tile] = c;
  }

  u16 vreg[80];
  #pragma unroll
  for (int vt = 0; vt < 10; ++vt) {
    const u16* vp = base + (size_t)(sJB[vt] * 8) * 1536 + 1024 + hh * 64 + t;
    #pragma unroll
    for (int j = 0; j < 8; ++j) vreg[vt * 8 + j] = vp[(size_t)j * 1536];
  }

  f32x4 mx = {-3.0e38f, -3.0e38f, -3.0e38f, -3.0e38f};
  #pragma unroll
  for (int tile = 0; tile < 5; ++tile) {
    #pragma unroll
    for (int r = 0; r < 4; ++r) {
      float v = s[tile][r] * 0.125f + okm[tile];
      s[tile][r] = v;
      mx[r] = fmaxf(mx[r], v);
    }
  }
  #pragma unroll
  for (int off = 1; off < 16; off <<= 1) {
    #pragma unroll
    for (int r = 0; r < 4; ++r) mx[r] = fmaxf(mx[r], __shfl_xor(mx[r], off));
  }
  f32x4 sm = {0.f, 0.f, 0.f, 0.f};
  #pragma unroll
  for (int tile = 0; tile < 5; ++tile) {
    #pragma unroll
    for (int r = 0; r < 4; ++r) {
      float e = __expf(s[tile][r] - mx[r]);
      s[tile][r] = e;
      sm[r] += e;
    }
  }
  #pragma unroll
  for (int off = 1; off < 16; off <<= 1) {
    #pragma unroll
    for (int r = 0; r < 4; ++r) sm[r] += __shfl_xor(sm[r], off);
  }

  #pragma unroll
  for (int tile = 0; tile < 5; ++tile)
    #pragma unroll
    for (int r = 0; r < 4; ++r)
      Pl[(quad * 4 + r) * 104 + tile * 16 + l15] = f2b(s[tile][r]);

  #pragma unroll
  for (int vt = 0; vt < 10; ++vt) {
    short8 w;
    #pragma unroll
    for (int j = 0; j < 8; ++j) ((u16*)&w)[j] = (short)vreg[vt * 8 + j];
    *(short8*)&Vt[t * 104 + vt * 8] = w;
  }
  __syncthreads();

  f32x4 o[4];
  #pragma unroll
  for (int dn = 0; dn < 4; ++dn) o[dn] = (f32x4){0.f, 0.f, 0.f, 0.f};
  #pragma unroll
  for (int ks = 0; ks < 3; ++ks) {
    short8 ap = *(const short8*)&Pl[l15 * 104 + ks * 32 + quad * 8];
    #pragma unroll
    for (int dn = 0; dn < 4; ++dn) {
      short8 bv = *(const short8*)&Vt[(dn * 16 + l15) * 104 + ks * 32 + quad * 8];
      o[dn] = __builtin_amdgcn_mfma_f32_16x16x32_bf16(ap, bv, o[dn], 0, 0, 0);
    }
  }

  if (quad < 2) {
    #pragma unroll
    for (int r = 0; r < 4; ++r) {
      int qi = quad * 4 + r;
      float inv = 1.f / sm[r];
      u16* op = av + ((size_t)b * Sp + n * 8 + qi) * 512 + hh * 64 + l15;
      #pragma unroll
      for (int dn = 0; dn < 4; ++dn)
        op[dn * 16] = f2b(o[dn][r] * inv);
    }
  }
}

// ---------- VAE head ----------
__global__ __launch_bounds__(512) void head_k(const float* __restrict__ h,
    const float* __restrict__ Wm, const float* __restrict__ bm,
    const float* __restrict__ Wlv, const float* __restrict__ blv,
    const float* __restrict__ eps, float* __restrict__ z, float* out_elbo)
{
  __shared__ float red[512];
  int t = threadIdx.x;
  int b = t >> 4, i = t & 15;
  const float* p = h + (size_t)b * SPENC * 512;
  float am = bm[i], al = blv[i];
  for (int c = 0; c < 512; ++c) {
    float pv = p[c];
    am += pv * Wm[c * 16 + i];
    al += pv * Wlv[c * 16 + i];
  }
  z[t] = am + eps[t] * expf(0.5f * al);
  red[t] = -0.5f * (1.f + al - am * am - expf(al));
  __syncthreads();
  for (int o = 256; o > 0; o >>= 1) { if (t < o) red[t] += red[t + o]; __syncthreads(); }
  if (t == 0) out_elbo[0] = red[0] * (1.f / 32.f);
}

// ---------- seq ----------
__global__ __launch_bounds__(256) void seq_k(const float* __restrict__ z, const float* __restrict__ We,
    const float* __restrict__ be, float* __restrict__ seq)
{
  int gid = blockIdx.x * 256 + threadIdx.x;
  int b = gid >> 11, c = gid & 2047;
  float acc = be[c];
  #pragma unroll
  for (int i = 0; i < 16; ++i) acc += z[b * 16 + i] * We[i * 2048 + c];
  seq[gid] = acc;
}

// ---------- decoder init: h fp32 + hb bf16 ----------
__global__ __launch_bounds__(256) void decinit_k(const float* __restrict__ seq, const float* __restrict__ Wc,
    const float* __restrict__ bc, const float* __restrict__ emb, float* __restrict__ h, u16* __restrict__ hb)
{
  size_t gid = (size_t)blockIdx.x * 256 + threadIdx.x;
  int dd = (int)(gid & 511);
  size_t rs = gid >> 9;
  int s = (int)(rs & 1023);
  int b = (int)(rs >> 10);
  float v = seq[b * 2048 + s] * Wc[dd] + seq[b * 2048 + 1024 + s] * Wc[512 + dd]
          + bc[dd] + emb[(size_t)s * 512 + dd];
  h[gid] = v;
  hb[gid] = f2b(v);
}

// ---------- final: out[M,16] = hb[M,512] @ Wseq[512,16] + bs, via MFMA ----------
__global__ __launch_bounds__(256) void finalm_k(const u16* __restrict__ hb, const float* __restrict__ Ws,
    const float* __restrict__ bs, float* __restrict__ out)
{
  __shared__ __align__(16) u16 Wt[16 * 520];
  int t = threadIdx.x;
  for (int e = t; e < 8192; e += 256) {
    int k = e >> 4, n = e & 15;
    Wt[n * 520 + k] = f2b(Ws[e]);
  }
  __syncthreads();
  int lane = t & 63, wave = t >> 6;
  int quad = lane >> 4, l15 = lane & 15;
  int m0 = blockIdx.x * 64 + wave * 16;
  const u16* arow = hb + (size_t)(m0 + l15) * 512 + quad * 8;
  f32x4 acc = (f32x4){0.f, 0.f, 0.f, 0.f};
  #pragma unroll
  for (int ks = 0; ks < 16; ++ks) {
    short8 af = *(const short8*)(arow + ks * 32);
    short8 bf = *(const short8*)&Wt[l15 * 520 + ks * 32 + quad * 8];
    acc = __builtin_amdgcn_mfma_f32_16x16x32_bf16(af, bf, acc, 0, 0, 0);
  }
  #pragma unroll
  for (int r = 0; r < 4; ++r)
    out[(size_t)(m0 + quad * 4 + r) * 16 + l15] = acc[r] + bs[l15];
}

extern "C" void kernel_launch(void* const* d_in, const int* in_sizes, int n_in,
                              void* d_out, int out_size, void* d_ws, size_t ws_size,
                              hipStream_t stream) {
  float* out = (float*)d_out;
  (void)out_size; (void)ws_size;

  static const int EXP_DICT[30] = {
    524288, 512, 524800, 524288, 8192, 512, 7864320, 15360, 2621440, 5120,
    5120, 5120, 10485760, 20480, 10485760, 5120, 5120, 5120, 8192, 16,
    8192, 16, 32768, 2048, 1024, 512, 8192, 16, 387, 384 };
  bool dict_ok = (n_in == 30);
  if (dict_ok) for (int i = 0; i < 30; ++i) if (in_sizes[i] != EXP_DICT[i]) { dict_ok = false; break; }
  if (!dict_ok) { beacon_k<<<1, 64, 0, stream>>>(out); return; }

  const float* x      = (const float*)d_in[0];
  const float* eps    = (const float*)d_in[1];
  const float* emb_in = (const float*)d_in[2];
  const float* emb_out= (const float*)d_in[3];
  const float* W_data = (const float*)d_in[4];
  const float* b_data = (const float*)d_in[5];
  const float* Wqkv   = (const float*)d_in[6];
  const float* bqkv   = (const float*)d_in[7];
  const float* Wo     = (const float*)d_in[8];
  const float* bo     = (const float*)d_in[9];
  const float* ln1g   = (const float*)d_in[10];
  const float* ln1b   = (const float*)d_in[11];
  const float* W1     = (const float*)d_in[12];
  const float* b1     = (const float*)d_in[13];
  const float* W2     = (const float*)d_in[14];
  const float* b2     = (const float*)d_in[15];
  const float* ln2g   = (const float*)d_in[16];
  const float* ln2b   = (const float*)d_in[17];
  const float* Wm     = (const float*)d_in[18];
  const float* bm     = (const float*)d_in[19];
  const float* Wlv    = (const float*)d_in[20];
  const float* blv    = (const float*)d_in[21];
  const float* Wexp   = (const float*)d_in[22];
  const float* bexp   = (const float*)d_in[23];
  const float* Wconv  = (const float*)d_in[24];
  const float* bconv  = (const float*)d_in[25];
  const float* Wseq   = (const float*)d_in[26];
  const float* bseq   = (const float*)d_in[27];
  const int* rand_enc = (const int*)d_in[28];
  const int* rand_dec = (const int*)d_in[29];

  // ---- workspace carve (~194.5 MB; proven-safe envelope 203 MB) ----
  char* ws = (char*)d_ws;
  float* h     = (float*)ws;
  u16*   hb    = (u16*)(ws + 67633152);
  u16*   WTqkv = (u16*)(ws + 101449728);
  u16*   WTo   = (u16*)(ws + 117178368);
  u16*   WT1l  = (u16*)(ws + 122421248);
  u16*   WT2l  = (u16*)(ws + 124518400);
  u16*   qkvb  = (u16*)(ws + 126615552);
  u16*   avb   = (u16*)(ws + 126615552 + 50724864);
  u16*   ffnb  = (u16*)(ws + 126615552);             // union reuse
  float* seqb  = (float*)(ws + 194248704);
  float* z     = (float*)(ws + 194510848);

  // ---- persistent weight transpose+convert (qkv, o for all 10 layers) ----
  tr_k<<<dim3(512 / 32, 1536 / 32, 10), 256, 0, stream>>>(Wqkv, WTqkv, 512, 1536);
  tr_k<<<dim3(512 / 32, 512 / 32, 10), 256, 0, stream>>>(Wo, WTo, 512, 512);

  // ===== encoder: M=33024 =====
  {
    const int M = MENC;
    embed_k<<<(M * 512) / 256, 256, 0, stream>>>(x, W_data, b_data, emb_in, h, hb);
    for (int i = 0; i < 5; ++i) {
      // attention path: 2 chunks of 16 batches (Mc=16512)
      for (int bc = 0; bc < 2; ++bc) {
        size_t roff = (size_t)bc * 16 * SPENC * 512;
        const int Mc = 16 * SPENC;  // 16512
        const int ty = 129;         // 16512/128
        mgemm_k<false><<<dim3(6, ty), 512, 0, stream>>>(
            hb + roff, WTqkv + (size_t)i * 512 * 1536, bqkv + (size_t)i * 1536, qkvb, Mc, 1536, 512, 512, 512);
        attnm_k<<<16 * 8 * NBE, 64, 0, stream>>>(qkvb, avb, rand_enc, SENC, SPENC, NBE);
        // fused Wo + residual + LN1 (128-row tile, grid 129)
        mgemmln_k<<<ty, 512, 0, stream>>>(
            avb, WTo + (size_t)i * 512 * 512, bo + (size_t)i * 512,
            h + roff, hb + roff, ln1g + (size_t)i * 512, ln1b + (size_t)i * 512, Mc, 512, 512);
      }
      // per-layer FFN weight transposes
      tr_k<<<dim3(512 / 32, 2048 / 32, 1), 256, 0, stream>>>(W1 + (size_t)i * 512 * 2048, WT1l, 512, 2048);
      tr_k<<<dim3(2048 / 32, 512 / 32, 1), 256, 0, stream>>>(W2 + (size_t)i * 2048 * 512, WT2l, 2048, 512);
      // FFN: 2 chunks of 16512 (ffnb = 67.6 MB exactly)
      for (int cc = 0; cc < 2; ++cc) {
        size_t off = (size_t)cc * 16512;
        const int Mc = 16512;
        const int ty = 129;
        mgemm_k<true><<<dim3(8, ty), 512, 0, stream>>>(
            hb + off * 512, WT1l, b1 + (size_t)i * 2048, ffnb, Mc, 2048, 512, 512, 512);
        // fused W2 + residual + LN2 (128-row tile, grid 129)
        mgemmln_k<<<ty, 512, 0, stream>>>(
            ffnb, WT2l, b2 + (size_t)i * 512,
            h + off * 512, hb + off * 512, ln2g + (size_t)i * 512, ln2b + (size_t)i * 512, Mc, 2048, 2048);
      }
    }
  }

  // ===== VAE head =====
  head_k<<<1, 512, 0, stream>>>(h, Wm, bm, Wlv, blv, eps, z, out + 524288);
  seq_k<<<256, 256, 0, stream>>>(z, Wexp, bexp, seqb);
  decinit_k<<<(MDEC * 512) / 256, 256, 0, stream>>>(seqb, Wconv, bconv, emb_out, h, hb);

  // ===== decoder: M=32768 =====
  {
    for (int i = 5; i < 10; ++i) {
      for (int bc = 0; bc < 2; ++bc) {
        size_t roff = (size_t)bc * 16 * SDEC * 512;
        const int Mc = 16 * SDEC;  // 16384
        const int ty = 128;
        mgemm_k<false><<<dim3(6, ty), 512, 0, stream>>>(
            hb + roff, WTqkv + (size_t)i * 512 * 1536, bqkv + (size_t)i * 1536, qkvb, Mc, 1536, 512, 512, 512);
        attnm_k<<<16 * 8 * NBD, 64, 0, stream>>>(qkvb, avb, rand_dec, SDEC, SDEC, NBD);
        mgemmln_k<<<ty, 512, 0, stream>>>(
            avb, WTo + (size_t)i * 512 * 512, bo + (size_t)i * 512,
            h + roff, hb + roff, ln1g + (size_t)i * 512, ln1b + (size_t)i * 512, Mc, 512, 512);
      }
      tr_k<<<dim3(512 / 32, 2048 / 32, 1), 256, 0, stream>>>(W1 + (size_t)i * 512 * 2048, WT1l, 512, 2048);
      tr_k<<<dim3(2048 / 32, 512 / 32, 1), 256, 0, stream>>>(W2 + (size_t)i * 2048 * 512, WT2l, 2048, 512);
      for (int cc = 0; cc < 2; ++cc) {
        size_t off = (size_t)cc * 16384;
        const int Mc = 16384;
        const int ty = 128;
        mgemm_k<true><<<dim3(8, ty), 512, 0, stream>>>(
            hb + off * 512, WT1l, b1 + (size_t)i * 2048, ffnb, Mc, 2048, 512, 512, 512);
        mgemmln_k<<<ty, 512, 0, stream>>>(
            ffnb, WT2l, b2 + (size_t)i * 512,
            h + off * 512, hb + off * 512, ln2g + (size_t)i * 512, ln2b + (size_t)i * 512, Mc, 2048, 2048);
      }
    }
  }

  // ===== output =====
  finalm_k<<<MDEC / 64, 256, 0, stream>>>(hb, Wseq, bseq, out);
}

// Round 14
// 5904.102 us; speedup vs baseline: 1.9489x; 1.9489x over previous
//
#include <hip/hip_runtime.h>

typedef unsigned short u16;
typedef __attribute__((ext_vector_type(8))) short short8;
typedef __attribute__((ext_vector_type(4))) float f32x4;

__device__ __forceinline__ float b2f(u16 h) {
  union { unsigned int u; float f; } v; v.u = ((unsigned int)h) << 16; return v.f;
}
__device__ __forceinline__ u16 f2b(float f) {
  union { float f; unsigned int u; } v; v.f = f;
  return (u16)((v.u + 0x7fffu + ((v.u >> 16) & 1u)) >> 16);
}

// async global->LDS, 16B per lane; dst must be wave-base + lane*16 (m97 pattern)
__device__ __forceinline__ void gload16(const u16* g, u16* l) {
  __builtin_amdgcn_global_load_lds(
      (const __attribute__((address_space(1))) void*)g,
      (__attribute__((address_space(3))) void*)l, 16, 0, 0);
}

#define SENC 1025
#define SPENC 1032
#define NBE 129
#define SDEC 1024
#define NBD 128
#define BATCH 32
#define MENC (BATCH * SPENC)  /* 33024 */
#define MDEC (BATCH * SDEC)   /* 32768 */

// ---------- beacon ----------
__global__ void beacon_k(float* out) { if (threadIdx.x == 0) out[0] = 1000.0f; }

// ---------- weight transpose + bf16 convert: WT[n][k] = bf16(W[k][n]) ----------
__global__ __launch_bounds__(256) void tr_k(const float* __restrict__ W, u16* __restrict__ WT, int K, int N)
{
  __shared__ float sm[32][33];
  int k0 = blockIdx.x * 32, n0 = blockIdx.y * 32;
  const float* Wz = W + (size_t)blockIdx.z * K * N;
  u16* WTz = WT + (size_t)blockIdx.z * K * N;
  int r = threadIdx.x >> 3, c0 = (threadIdx.x & 7) * 4;
  float4 v = *(const float4*)&Wz[(size_t)(k0 + r) * N + n0 + c0];
  sm[r][c0] = v.x; sm[r][c0 + 1] = v.y; sm[r][c0 + 2] = v.z; sm[r][c0 + 3] = v.w;
  __syncthreads();
  ushort4 u;
  u.x = f2b(sm[c0][r]); u.y = f2b(sm[c0 + 1][r]); u.z = f2b(sm[c0 + 2][r]); u.w = f2b(sm[c0 + 3][r]);
  *(ushort4*)&WTz[(size_t)(n0 + r) * K + k0 + c0] = u;
}

// ---------- embed: h fp32 + hb bf16 ----------
__global__ __launch_bounds__(256) void embed_k(const float* __restrict__ x, const float* __restrict__ Wd,
    const float* __restrict__ bd, const float* __restrict__ emb, float* __restrict__ h, u16* __restrict__ hb)
{
  size_t gid = (size_t)blockIdx.x * 256 + threadIdx.x;  // MENC*512
  int dd = (int)(gid & 511);
  size_t rs = gid >> 9;
  int s = (int)(rs % SPENC);
  int b = (int)(rs / SPENC);
  float v;
  if (s == 0) {
    v = emb[dd];
  } else if (s < SENC) {
    float acc = bd[dd];
    const float* xr = x + ((size_t)b * 1024 + (s - 1)) * 16;
    #pragma unroll
    for (int j = 0; j < 16; ++j) acc += xr[j] * Wd[j * 512 + dd];
    v = acc + emb[(size_t)s * 512 + dd];
  } else {
    v = 0.f;
  }
  h[gid] = v;
  hb[gid] = f2b(v);
}

// ---------- MFMA bf16 GEMM, 128x256 tile, 512 threads (8 waves) ----------
// Triple-buffered LDS + counted vmcnt; output bf16 + bias (+ReLU).
// LDS chunk (16B = 8 bf16): logical k-chunk c of row r stored at slot r*4 + (c ^ ((r>>1)&3)).
template<bool RELU>
__global__ __launch_bounds__(512) void mgemm_k(const u16* __restrict__ A, const u16* __restrict__ WT,
    const float* __restrict__ bias, u16* __restrict__ C,
    int M, int N, int Kc, int lda, int ldb)
{
  __shared__ __align__(16) u16 sA[3][128 * 32];   // 24 KB
  __shared__ __align__(16) u16 sB[3][256 * 32];   // 48 KB
  int t = threadIdx.x;

  // bijective XCD-aware remap of the flattened (x,y) id
  int gx = gridDim.x;
  int nwg = gx * gridDim.y;
  int flat = blockIdx.y * gx + blockIdx.x;
  int q = nwg >> 3, rr = nwg & 7;
  int xcd = flat & 7, idx = flat >> 3;
  int swz = (xcd < rr ? xcd * (q + 1) : rr * (q + 1) + (xcd - rr) * q) + idx;
  int bx = swz % gx, by = swz / gx;

  int n0 = bx * 256, m0 = by * 128;
  int lane = t & 63, wave = t >> 6;            // 8 waves: 2M x 4N
  int wm = (wave >> 2) * 64, wn = (wave & 3) * 64;
  int quad = lane >> 4, l15 = lane & 15;

  int rA = t >> 2, sc = t & 3;
  int cA = sc ^ ((rA >> 1) & 3);
  int raA = m0 + rA; raA = raA < M ? raA : M - 1;
  const u16* gA  = A  + (size_t)raA * lda + cA * 8;
  const u16* gB0 = WT + (size_t)(n0 + rA) * ldb + cA * 8;       // rows 0..127
  const u16* gB1 = WT + (size_t)(n0 + 128 + rA) * ldb + cA * 8; // rows 128..255 (same xor)

  f32x4 acc[4][4];
  #pragma unroll
  for (int i = 0; i < 4; ++i)
    #pragma unroll
    for (int j = 0; j < 4; ++j) acc[i][j] = (f32x4){0.f, 0.f, 0.f, 0.f};

  const int nt = Kc >> 5;
  gload16(gA,      &sA[0][t * 8]);
  gload16(gB0,     &sB[0][t * 8]);
  gload16(gB1,     &sB[0][(512 + t) * 8]);
  gload16(gA + 32, &sA[1][t * 8]);
  gload16(gB0 + 32,&sB[1][t * 8]);
  gload16(gB1 + 32,&sB[1][(512 + t) * 8]);

  int cur = 0;
  for (int tt = 0; tt < nt; ++tt) {
    if (tt < nt - 1) {
      asm volatile("s_waitcnt vmcnt(3)" ::: "memory");
    } else {
      asm volatile("s_waitcnt vmcnt(0)" ::: "memory");
    }
    __builtin_amdgcn_s_barrier();
    asm volatile("" ::: "memory");
    if (tt + 2 < nt) {
      int k0 = (tt + 2) << 5;
      int nb = tt + 2; nb -= (nb / 3) * 3;               // (tt+2) % 3
      gload16(gA + k0,  &sA[nb][t * 8]);
      gload16(gB0 + k0, &sB[nb][t * 8]);
      gload16(gB1 + k0, &sB[nb][(512 + t) * 8]);
    }
    short8 af[4], bf[4];
    #pragma unroll
    for (int i = 0; i < 4; ++i) {
      int ra = wm + i * 16 + l15;
      af[i] = *(const short8*)&sA[cur][ra * 32 + (quad ^ ((ra >> 1) & 3)) * 8];
    }
    #pragma unroll
    for (int j = 0; j < 4; ++j) {
      int rb = wn + j * 16 + l15;
      bf[j] = *(const short8*)&sB[cur][rb * 32 + (quad ^ ((rb >> 1) & 3)) * 8];
    }
    __builtin_amdgcn_s_setprio(1);
    #pragma unroll
    for (int i = 0; i < 4; ++i)
      #pragma unroll
      for (int j = 0; j < 4; ++j)
        acc[i][j] = __builtin_amdgcn_mfma_f32_16x16x32_bf16(af[i], bf[j], acc[i][j], 0, 0, 0);
    __builtin_amdgcn_s_setprio(0);
    cur = (cur == 2) ? 0 : cur + 1;
  }

  #pragma unroll
  for (int i = 0; i < 4; ++i) {
    int mBase = m0 + wm + i * 16 + quad * 4;
    #pragma unroll
    for (int r = 0; r < 4; ++r) {
      int m = mBase + r;
      if (m < M) {
        #pragma unroll
        for (int j = 0; j < 4; ++j) {
          int n = n0 + wn + j * 16 + l15;
          float v = acc[i][j][r] + bias[n];
          if (RELU) v = fmaxf(v, 0.f);
          C[(size_t)m * N + n] = f2b(v);
        }
      }
    }
  }
}

// ---------- fused GEMM(N=512) + residual + LayerNorm, 128M x 512N tile ----------
// One block owns 128 rows x ALL 512 cols; grid = M/128. 8 waves (2M x 4N),
// per-wave 64x128 (acc[4][8]). Double-buffered LDS (R1-proven loop).
// Epilogue: v = acc + bias + h (f32); row mean/var via quad-shfl + 4-wide LDS
// cross-wave reduce; writes h (fp32) and hb (bf16). Requires M % 128 == 0.
__global__ __launch_bounds__(512) void mgemmln_k(const u16* __restrict__ A, const u16* __restrict__ WT,
    const float* __restrict__ bias, float* __restrict__ h, u16* __restrict__ hb,
    const float* __restrict__ g, const float* __restrict__ bbv_,
    int M, int Kc, int lda)
{
  __shared__ __align__(16) u16 sA[2][128 * 32];   // 16 KB
  __shared__ __align__(16) u16 sB[2][512 * 32];   // 64 KB
  __shared__ float redS[128][4], redQ[128][4];    // 4 KB
  int t = threadIdx.x;
  int m0 = blockIdx.x * 128;
  int lane = t & 63, wave = t >> 6;               // 8 waves: 2M x 4N
  int wm = (wave >> 2) * 64, wn = (wave & 3) * 128;
  int quad = lane >> 4, l15 = lane & 15;
  int wnid = wave & 3;

  // staging: A 1 issue (rows 0..127), B 4 issues (rows 0..511); same xor slotting
  int rA = t >> 2, sc = t & 3;
  int cA = sc ^ ((rA >> 1) & 3);
  const u16* gA = A + (size_t)(m0 + rA) * lda + cA * 8;
  const u16* gB = WT + (size_t)rA * Kc + cA * 8;  // +128*Kc per extra issue (xor invariant)

  f32x4 acc[4][8];
  #pragma unroll
  for (int i = 0; i < 4; ++i)
    #pragma unroll
    for (int j = 0; j < 8; ++j) acc[i][j] = (f32x4){0.f, 0.f, 0.f, 0.f};

  const int nt = Kc >> 5;
  // prologue: stage tile 0 into buf 0
  gload16(gA, &sA[0][t * 8]);
  #pragma unroll
  for (int b4 = 0; b4 < 4; ++b4)
    gload16(gB + (size_t)b4 * 128 * Kc, &sB[0][(b4 * 512 + t) * 8]);
  int cur = 0;
  for (int tt = 0; tt < nt; ++tt) {
    __syncthreads();  // drains vmcnt(0): buf[cur] ready; prior reads of buf[cur^1] done
    if (tt + 1 < nt) {
      int k0 = (tt + 1) << 5;
      gload16(gA + k0, &sA[cur ^ 1][t * 8]);
      #pragma unroll
      for (int b4 = 0; b4 < 4; ++b4)
        gload16(gB + (size_t)b4 * 128 * Kc + k0, &sB[cur ^ 1][(b4 * 512 + t) * 8]);
    }
    short8 af[4], bf[8];
    #pragma unroll
    for (int i = 0; i < 4; ++i) {
      int ra = wm + i * 16 + l15;
      af[i] = *(const short8*)&sA[cur][ra * 32 + (quad ^ ((ra >> 1) & 3)) * 8];
    }
    #pragma unroll
    for (int j = 0; j < 8; ++j) {
      int rb = wn + j * 16 + l15;
      bf[j] = *(const short8*)&sB[cur][rb * 32 + (quad ^ ((rb >> 1) & 3)) * 8];
    }
    __builtin_amdgcn_s_setprio(1);
    #pragma unroll
    for (int i = 0; i < 4; ++i)
      #pragma unroll
      for (int j = 0; j < 8; ++j)
        acc[i][j] = __builtin_amdgcn_mfma_f32_16x16x32_bf16(af[i], bf[j], acc[i][j], 0, 0, 0);
    __builtin_amdgcn_s_setprio(0);
    cur ^= 1;
  }

  // ---------- epilogue: residual add + row stats ----------
  float bsv[8];
  #pragma unroll
  for (int j = 0; j < 8; ++j) bsv[j] = bias[wn + j * 16 + l15];

  #pragma unroll
  for (int i = 0; i < 4; ++i) {
    #pragma unroll
    for (int r = 0; r < 4; ++r) {
      int lr = wm + i * 16 + quad * 4 + r;
      const float* hrow = h + (size_t)(m0 + lr) * 512 + wn + l15;
      float s = 0.f, qq = 0.f;
      #pragma unroll
      for (int j = 0; j < 8; ++j) {
        float v = acc[i][j][r] + bsv[j] + hrow[j * 16];
        acc[i][j][r] = v;
        s += v; qq += v * v;
      }
      #pragma unroll
      for (int off = 1; off < 16; off <<= 1) {
        s += __shfl_xor(s, off);
        qq += __shfl_xor(qq, off);
      }
      if (l15 == 0) { redS[lr][wnid] = s; redQ[lr][wnid] = qq; }
    }
  }
  __syncthreads();
  float gv[8], bv[8];
  #pragma unroll
  for (int j = 0; j < 8; ++j) {
    gv[j] = g[wn + j * 16 + l15];
    bv[j] = bbv_[wn + j * 16 + l15];
  }
  #pragma unroll
  for (int i = 0; i < 4; ++i) {
    #pragma unroll
    for (int r = 0; r < 4; ++r) {
      int lr = wm + i * 16 + quad * 4 + r;
      float s = redS[lr][0] + redS[lr][1] + redS[lr][2] + redS[lr][3];
      float qq = redQ[lr][0] + redQ[lr][1] + redQ[lr][2] + redQ[lr][3];
      float mean = s * (1.f / 512.f);
      float var = fmaxf(qq * (1.f / 512.f) - mean * mean, 0.f);
      float rinv = rsqrtf(var + 1e-5f);
      float* hrow = h + (size_t)(m0 + lr) * 512 + wn + l15;
      u16* hbrow = hb + (size_t)(m0 + lr) * 512 + wn + l15;
      #pragma unroll
      for (int j = 0; j < 8; ++j) {
        float o = (acc[i][j][r] - mean) * rinv * gv[j] + bv[j];
        hrow[j * 16] = o;
        hbrow[j * 16] = f2b(o);
      }
    }
  }
}

// ---------- sparse block attention, MFMA version: one wave per (b, h, n) ----------
__global__ __launch_bounds__(64) void attnm_k(const u16* __restrict__ qkv, u16* __restrict__ av,
    const int* __restrict__ rnd, int S, int Sp, int nb)
{
  __shared__ __align__(16) u16 Vt[64 * 104];
  __shared__ __align__(16) u16 Pl[16 * 104];
  __shared__ int sJB[10], sVD[10];
  int t = threadIdx.x;
  int n = blockIdx.x % nb;
  int r1 = blockIdx.x / nb;
  int hh = r1 & 7, b = r1 >> 3;
  const u16* base = qkv + (size_t)b * Sp * 1536;
  int l15 = t & 15, quad = t >> 4;

  if (t < 10) {
    int jb, vd;
    if (t < 2) { jb = t; vd = 1; }
    else if (t < 7) {
      int w = n + t - 4;
      vd = (w >= 0 && w < nb) ? 1 : 0;
      jb = w < 0 ? 0 : (w > nb - 1 ? nb - 1 : w);
    } else { jb = rnd[n * 3 + t - 7]; vd = 1; }
    sJB[t] = jb; sVD[t] = vd;
  }
  {
    f32x4 zz = {0.f, 0.f, 0.f, 0.f};
    *(f32x4*)&Vt[t * 104 + 80] = zz;
    *(f32x4*)&Vt[t * 104 + 88] = zz;
    if (t < 16) {
      *(f32x4*)&Pl[t * 104 + 80] = zz;
      *(f32x4*)&Pl[t * 104 + 88] = zz;
    }
  }
  __syncthreads();

  short8 aq0, aq1;
  {
    const u16* qp = base + (size_t)(n * 8 + (l15 & 7)) * 1536 + hh * 64 + quad * 8;
    aq0 = *(const short8*)qp;
    aq1 = *(const short8*)(qp + 32);
  }

  f32x4 s[5];
  float okm[5];
  #pragma unroll
  for (int tile = 0; tile < 5; ++tile) {
    int kb = tile * 2 + (l15 >> 3);
    int tok = sJB[kb] * 8 + (l15 & 7);
    okm[tile] = (sVD[kb] && tok < S) ? 0.f : -3.0e38f;
    const u16* kp = base + (size_t)tok * 1536 + 512 + hh * 64 + quad * 8;
    short8 k0 = *(const short8*)kp;
    short8 k1 = *(const short8*)(kp + 32);
    f32x4 c = {0.f, 0.f, 0.f, 0.f};
    c = __builtin_amdgcn_mfma_f32_16x16x32_bf16(aq0, k0, c, 0, 0, 0);
    c = __builtin_amdgcn_mfma_f32_16x16x32_bf16(aq1, k1, c, 0, 0, 0);
    s[tile] = c;
  }

  u16 vreg[80];
  #pragma unroll
  for (int vt = 0; vt < 10; ++vt) {
    const u16* vp = base + (size_t)(sJB[vt] * 8) * 1536 + 1024 + hh * 64 + t;
    #pragma unroll
    for (int j = 0; j < 8; ++j) vreg[vt * 8 + j] = vp[(size_t)j * 1536];
  }

  f32x4 mx = {-3.0e38f, -3.0e38f, -3.0e38f, -3.0e38f};
  #pragma unroll
  for (int tile = 0; tile < 5; ++tile) {
    #pragma unroll
    for (int r = 0; r < 4; ++r) {
      float v = s[tile][r] * 0.125f + okm[tile];
      s[tile][r] = v;
      mx[r] = fmaxf(mx[r], v);
    }
  }
  #pragma unroll
  for (int off = 1; off < 16; off <<= 1) {
    #pragma unroll
    for (int r = 0; r < 4; ++r) mx[r] = fmaxf(mx[r], __shfl_xor(mx[r], off));
  }
  f32x4 sm = {0.f, 0.f, 0.f, 0.f};
  #pragma unroll
  for (int tile = 0; tile < 5; ++tile) {
    #pragma unroll
    for (int r = 0; r < 4; ++r) {
      float e = __expf(s[tile][r] - mx[r]);
      s[tile][r] = e;
      sm[r] += e;
    }
  }
  #pragma unroll
  for (int off = 1; off < 16; off <<= 1) {
    #pragma unroll
    for (int r = 0; r < 4; ++r) sm[r] += __shfl_xor(sm[r], off);
  }

  #pragma unroll
  for (int tile = 0; tile < 5; ++tile)
    #pragma unroll
    for (int r = 0; r < 4; ++r)
      Pl[(quad * 4 + r) * 104 + tile * 16 + l15] = f2b(s[tile][r]);

  #pragma unroll
  for (int vt = 0; vt < 10; ++vt) {
    short8 w;
    #pragma unroll
    for (int j = 0; j < 8; ++j) ((u16*)&w)[j] = (short)vreg[vt * 8 + j];
    *(short8*)&Vt[t * 104 + vt * 8] = w;
  }
  __syncthreads();

  f32x4 o[4];
  #pragma unroll
  for (int dn = 0; dn < 4; ++dn) o[dn] = (f32x4){0.f, 0.f, 0.f, 0.f};
  #pragma unroll
  for (int ks = 0; ks < 3; ++ks) {
    short8 ap = *(const short8*)&Pl[l15 * 104 + ks * 32 + quad * 8];
    #pragma unroll
    for (int dn = 0; dn < 4; ++dn) {
      short8 bv = *(const short8*)&Vt[(dn * 16 + l15) * 104 + ks * 32 + quad * 8];
      o[dn] = __builtin_amdgcn_mfma_f32_16x16x32_bf16(ap, bv, o[dn], 0, 0, 0);
    }
  }

  if (quad < 2) {
    #pragma unroll
    for (int r = 0; r < 4; ++r) {
      int qi = quad * 4 + r;
      float inv = 1.f / sm[r];
      u16* op = av + ((size_t)b * Sp + n * 8 + qi) * 512 + hh * 64 + l15;
      #pragma unroll
      for (int dn = 0; dn < 4; ++dn)
        op[dn * 16] = f2b(o[dn][r] * inv);
    }
  }
}

// ---------- VAE head ----------
__global__ __launch_bounds__(512) void head_k(const float* __restrict__ h,
    const float* __restrict__ Wm, const float* __restrict__ bm,
    const float* __restrict__ Wlv, const float* __restrict__ blv,
    const float* __restrict__ eps, float* __restrict__ z, float* out_elbo)
{
  __shared__ float red[512];
  int t = threadIdx.x;
  int b = t >> 4, i = t & 15;
  const float* p = h + (size_t)b * SPENC * 512;
  float am = bm[i], al = blv[i];
  for (int c = 0; c < 512; ++c) {
    float pv = p[c];
    am += pv * Wm[c * 16 + i];
    al += pv * Wlv[c * 16 + i];
  }
  z[t] = am + eps[t] * expf(0.5f * al);
  red[t] = -0.5f * (1.f + al - am * am - expf(al));
  __syncthreads();
  for (int o = 256; o > 0; o >>= 1) { if (t < o) red[t] += red[t + o]; __syncthreads(); }
  if (t == 0) out_elbo[0] = red[0] * (1.f / 32.f);
}

// ---------- seq ----------
__global__ __launch_bounds__(256) void seq_k(const float* __restrict__ z, const float* __restrict__ We,
    const float* __restrict__ be, float* __restrict__ seq)
{
  int gid = blockIdx.x * 256 + threadIdx.x;
  int b = gid >> 11, c = gid & 2047;
  float acc = be[c];
  #pragma unroll
  for (int i = 0; i < 16; ++i) acc += z[b * 16 + i] * We[i * 2048 + c];
  seq[gid] = acc;
}

// ---------- decoder init: h fp32 + hb bf16 ----------
__global__ __launch_bounds__(256) void decinit_k(const float* __restrict__ seq, const float* __restrict__ Wc,
    const float* __restrict__ bc, const float* __restrict__ emb, float* __restrict__ h, u16* __restrict__ hb)
{
  size_t gid = (size_t)blockIdx.x * 256 + threadIdx.x;
  int dd = (int)(gid & 511);
  size_t rs = gid >> 9;
  int s = (int)(rs & 1023);
  int b = (int)(rs >> 10);
  float v = seq[b * 2048 + s] * Wc[dd] + seq[b * 2048 + 1024 + s] * Wc[512 + dd]
          + bc[dd] + emb[(size_t)s * 512 + dd];
  h[gid] = v;
  hb[gid] = f2b(v);
}

// ---------- final: out[M,16] = hb[M,512] @ Wseq[512,16] + bs, via MFMA ----------
__global__ __launch_bounds__(256) void finalm_k(const u16* __restrict__ hb, const float* __restrict__ Ws,
    const float* __restrict__ bs, float* __restrict__ out)
{
  __shared__ __align__(16) u16 Wt[16 * 520];
  int t = threadIdx.x;
  for (int e = t; e < 8192; e += 256) {
    int k = e >> 4, n = e & 15;
    Wt[n * 520 + k] = f2b(Ws[e]);
  }
  __syncthreads();
  int lane = t & 63, wave = t >> 6;
  int quad = lane >> 4, l15 = lane & 15;
  int m0 = blockIdx.x * 64 + wave * 16;
  const u16* arow = hb + (size_t)(m0 + l15) * 512 + quad * 8;
  f32x4 acc = (f32x4){0.f, 0.f, 0.f, 0.f};
  #pragma unroll
  for (int ks = 0; ks < 16; ++ks) {
    short8 af = *(const short8*)(arow + ks * 32);
    short8 bf = *(const short8*)&Wt[l15 * 520 + ks * 32 + quad * 8];
    acc = __builtin_amdgcn_mfma_f32_16x16x32_bf16(af, bf, acc, 0, 0, 0);
  }
  #pragma unroll
  for (int r = 0; r < 4; ++r)
    out[(size_t)(m0 + quad * 4 + r) * 16 + l15] = acc[r] + bs[l15];
}

extern "C" void kernel_launch(void* const* d_in, const int* in_sizes, int n_in,
                              void* d_out, int out_size, void* d_ws, size_t ws_size,
                              hipStream_t stream) {
  float* out = (float*)d_out;
  (void)out_size; (void)ws_size;

  static const int EXP_DICT[30] = {
    524288, 512, 524800, 524288, 8192, 512, 7864320, 15360, 2621440, 5120,
    5120, 5120, 10485760, 20480, 10485760, 5120, 5120, 5120, 8192, 16,
    8192, 16, 32768, 2048, 1024, 512, 8192, 16, 387, 384 };
  bool dict_ok = (n_in == 30);
  if (dict_ok) for (int i = 0; i < 30; ++i) if (in_sizes[i] != EXP_DICT[i]) { dict_ok = false; break; }
  if (!dict_ok) { beacon_k<<<1, 64, 0, stream>>>(out); return; }

  const float* x      = (const float*)d_in[0];
  const float* eps    = (const float*)d_in[1];
  const float* emb_in = (const float*)d_in[2];
  const float* emb_out= (const float*)d_in[3];
  const float* W_data = (const float*)d_in[4];
  const float* b_data = (const float*)d_in[5];
  const float* Wqkv   = (const float*)d_in[6];
  const float* bqkv   = (const float*)d_in[7];
  const float* Wo     = (const float*)d_in[8];
  const float* bo     = (const float*)d_in[9];
  const float* ln1g   = (const float*)d_in[10];
  const float* ln1b   = (const float*)d_in[11];
  const float* W1     = (const float*)d_in[12];
  const float* b1     = (const float*)d_in[13];
  const float* W2     = (const float*)d_in[14];
  const float* b2     = (const float*)d_in[15];
  const float* ln2g   = (const float*)d_in[16];
  const float* ln2b   = (const float*)d_in[17];
  const float* Wm     = (const float*)d_in[18];
  const float* bm     = (const float*)d_in[19];
  const float* Wlv    = (const float*)d_in[20];
  const float* blv    = (const float*)d_in[21];
  const float* Wexp   = (const float*)d_in[22];
  const float* bexp   = (const float*)d_in[23];
  const float* Wconv  = (const float*)d_in[24];
  const float* bconv  = (const float*)d_in[25];
  const float* Wseq   = (const float*)d_in[26];
  const float* bseq   = (const float*)d_in[27];
  const int* rand_enc = (const int*)d_in[28];
  const int* rand_dec = (const int*)d_in[29];

  // ---- workspace carve (~194.5 MB; proven-safe envelope 203 MB) ----
  // union region U = [126615552, 194248704), 67,633,152 B:
  //   attn phase: avbFull (33,816,576) at U+0  +  qkvb chunk (25,362,432) at U+33,816,576
  //               (sum 59,179,008 <= 67,633,152)
  //   FFN phase:  ffnb = U (16512 x 2048 bf16 = 67,633,152 exactly; avb dead by then)
  char* ws = (char*)d_ws;
  float* h     = (float*)ws;
  u16*   hb    = (u16*)(ws + 67633152);
  u16*   WTqkv = (u16*)(ws + 101449728);
  u16*   WTo   = (u16*)(ws + 117178368);
  u16*   WT1l  = (u16*)(ws + 122421248);
  u16*   WT2l  = (u16*)(ws + 124518400);
  u16*   avb   = (u16*)(ws + 126615552);             // full-M av
  u16*   qkvb  = (u16*)(ws + 126615552 + 33816576);  // per-chunk qkv (8 batches)
  u16*   ffnb  = (u16*)(ws + 126615552);             // union reuse (FFN phase)
  float* seqb  = (float*)(ws + 194248704);
  float* z     = (float*)(ws + 194510848);

  // ---- persistent weight transpose+convert (qkv, o for all 10 layers) ----
  tr_k<<<dim3(512 / 32, 1536 / 32, 10), 256, 0, stream>>>(Wqkv, WTqkv, 512, 1536);
  tr_k<<<dim3(512 / 32, 512 / 32, 10), 256, 0, stream>>>(Wo, WTo, 512, 512);

  // ===== encoder: M=33024 =====
  {
    const int M = MENC;
    embed_k<<<(M * 512) / 256, 256, 0, stream>>>(x, W_data, b_data, emb_in, h, hb);
    for (int i = 0; i < 5; ++i) {
      // attention path: 4 chunks of 8 batches (Mc=8256); av written into full-M avb
      for (int bc = 0; bc < 4; ++bc) {
        size_t roff = (size_t)bc * 8 * SPENC * 512;
        const int Mc = 8 * SPENC;  // 8256
        const int ty = 65;         // ceil(8256/128)
        mgemm_k<false><<<dim3(6, ty), 512, 0, stream>>>(
            hb + roff, WTqkv + (size_t)i * 512 * 1536, bqkv + (size_t)i * 1536, qkvb, Mc, 1536, 512, 512, 512);
        attnm_k<<<8 * 8 * NBE, 64, 0, stream>>>(qkvb, avb + roff, rand_enc, SENC, SPENC, NBE);
      }
      // fused Wo + residual + LN1 over FULL M (grid 258 -> full chip)
      mgemmln_k<<<M / 128, 512, 0, stream>>>(
          avb, WTo + (size_t)i * 512 * 512, bo + (size_t)i * 512,
          h, hb, ln1g + (size_t)i * 512, ln1b + (size_t)i * 512, M, 512, 512);
      // per-layer FFN weight transposes
      tr_k<<<dim3(512 / 32, 2048 / 32, 1), 256, 0, stream>>>(W1 + (size_t)i * 512 * 2048, WT1l, 512, 2048);
      tr_k<<<dim3(2048 / 32, 512 / 32, 1), 256, 0, stream>>>(W2 + (size_t)i * 2048 * 512, WT2l, 2048, 512);
      // FFN: 2 chunks of 16512 (ffnb = 67.6 MB exactly)
      for (int cc = 0; cc < 2; ++cc) {
        size_t off = (size_t)cc * 16512;
        const int Mc = 16512;
        const int ty = 129;
        mgemm_k<true><<<dim3(8, ty), 512, 0, stream>>>(
            hb + off * 512, WT1l, b1 + (size_t)i * 2048, ffnb, Mc, 2048, 512, 512, 512);
        mgemmln_k<<<ty, 512, 0, stream>>>(
            ffnb, WT2l, b2 + (size_t)i * 512,
            h + off * 512, hb + off * 512, ln2g + (size_t)i * 512, ln2b + (size_t)i * 512, Mc, 2048, 2048);
      }
    }
  }

  // ===== VAE head =====
  head_k<<<1, 512, 0, stream>>>(h, Wm, bm, Wlv, blv, eps, z, out + 524288);
  seq_k<<<256, 256, 0, stream>>>(z, Wexp, bexp, seqb);
  decinit_k<<<(MDEC * 512) / 256, 256, 0, stream>>>(seqb, Wconv, bconv, emb_out, h, hb);

  // ===== decoder: M=32768 =====
  {
    const int M = MDEC;
    for (int i = 5; i < 10; ++i) {
      for (int bc = 0; bc < 4; ++bc) {
        size_t roff = (size_t)bc * 8 * SDEC * 512;
        const int Mc = 8 * SDEC;  // 8192
        const int ty = 64;
        mgemm_k<false><<<dim3(6, ty), 512, 0, stream>>>(
            hb + roff, WTqkv + (size_t)i * 512 * 1536, bqkv + (size_t)i * 1536, qkvb, Mc, 1536, 512, 512, 512);
        attnm_k<<<8 * 8 * NBD, 64, 0, stream>>>(qkvb, avb + roff, rand_dec, SDEC, SDEC, NBD);
      }
      // fused Wo + residual + LN1 over FULL M (grid 256)
      mgemmln_k<<<M / 128, 512, 0, stream>>>(
          avb, WTo + (size_t)i * 512 * 512, bo + (size_t)i * 512,
          h, hb, ln1g + (size_t)i * 512, ln1b + (size_t)i * 512, M, 512, 512);
      tr_k<<<dim3(512 / 32, 2048 / 32, 1), 256, 0, stream>>>(W1 + (size_t)i * 512 * 2048, WT1l, 512, 2048);
      tr_k<<<dim3(2048 / 32, 512 / 32, 1), 256, 0, stream>>>(W2 + (size_t)i * 2048 * 512, WT2l, 2048, 512);
      for (int cc = 0; cc < 2; ++cc) {
        size_t off = (size_t)cc * 16384;
        const int Mc = 16384;
        const int ty = 128;
        mgemm_k<true><<<dim3(8, ty), 512, 0, stream>>>(
            hb + off * 512, WT1l, b1 + (size_t)i * 2048, ffnb, Mc, 2048, 512, 512, 512);
        mgemmln_k<<<ty, 512, 0, stream>>>(
            ffnb, WT2l, b2 + (size_t)i * 512,
            h + off * 512, hb + off * 512, ln2g + (size_t)i * 512, ln2b + (size_t)i * 512, Mc, 2048, 2048);
      }
    }
  }

  // ===== output =====
  finalm_k<<<MDEC / 64, 256, 0, stream>>>(hb, Wseq, bseq, out);
}